// Round 1
// baseline (391.388 us; speedup 1.0000x reference)
//
#include <hip/hip_runtime.h>

// StableTTLayer: TT forward, B=131072 samples.
// v = core0[0, i0, :]                         (32,)
// for t in 0..5: v = v @ cores_mid[t][:, i_{t+1}, :]   (norm trick cancels exactly)
// out = dot(v, core_last[:, i7, 0])
//
// Round 1: thread-per-sample baseline. v/acc fully in VGPRs (r-loop fully
// unrolled so no dynamic register indexing), float4 matrix gathers.
// Expected L2-BW-bound (~3.2 GB L2 traffic), ~90-130 us.

#define B_TOTAL 131072
#define ORDER 8
#define NDIM 64
#define RANK 32

__global__ __launch_bounds__(256) void tt_forward(
    const int* __restrict__ idx,      // B x 8 (int32)
    const float* __restrict__ core0,  // 64 x 32
    const float* __restrict__ mid,    // 6 x 32 x 64 x 32  elem [t][r][c][s] = t*65536 + r*2048 + c*32 + s
    const float* __restrict__ lastc,  // 32 x 64           elem [r][c] = r*64 + c
    float* __restrict__ out)          // B
{
    const int b = blockIdx.x * blockDim.x + threadIdx.x;
    if (b >= B_TOTAL) return;

    // init: v = core0[i0]
    int c0 = idx[b * ORDER + 0];
    c0 = min(max(c0, 0), NDIM - 1);

    float v[RANK];
    const float4* c0p = reinterpret_cast<const float4*>(core0 + c0 * RANK);
    #pragma unroll
    for (int q = 0; q < 8; ++q) {
        float4 f = c0p[q];
        v[4*q+0] = f.x; v[4*q+1] = f.y; v[4*q+2] = f.z; v[4*q+3] = f.w;
    }

    // 6 mid matvecs; t-loop rolled (code size / I-cache), r-loop fully
    // unrolled (v[] must stay in registers).
    for (int t = 0; t < 6; ++t) {
        int cc = idx[b * ORDER + t + 1];
        cc = min(max(cc, 0), NDIM - 1);
        const float* M = mid + (size_t)t * (RANK * NDIM * RANK) + (size_t)cc * RANK;

        float acc[RANK];
        #pragma unroll
        for (int s = 0; s < RANK; ++s) acc[s] = 0.0f;

        #pragma unroll
        for (int r = 0; r < RANK; ++r) {
            const float4* mp = reinterpret_cast<const float4*>(M + (size_t)r * (NDIM * RANK));
            const float vr = v[r];
            #pragma unroll
            for (int q = 0; q < 8; ++q) {
                float4 m = mp[q];
                acc[4*q+0] = fmaf(vr, m.x, acc[4*q+0]);
                acc[4*q+1] = fmaf(vr, m.y, acc[4*q+1]);
                acc[4*q+2] = fmaf(vr, m.z, acc[4*q+2]);
                acc[4*q+3] = fmaf(vr, m.w, acc[4*q+3]);
            }
        }
        #pragma unroll
        for (int s = 0; s < RANK; ++s) v[s] = acc[s];
    }

    // final: out = dot(v, core_last[:, i7, 0]), stride-64 column
    int c7 = idx[b * ORDER + 7];
    c7 = min(max(c7, 0), NDIM - 1);
    const float* lcol = lastc + c7;
    float o = 0.0f;
    #pragma unroll
    for (int r = 0; r < RANK; ++r) o = fmaf(v[r], lcol[(size_t)r * NDIM], o);
    out[b] = o;
}

extern "C" void kernel_launch(void* const* d_in, const int* in_sizes, int n_in,
                              void* d_out, int out_size, void* d_ws, size_t ws_size,
                              hipStream_t stream) {
    const int*   idx   = (const int*)d_in[0];    // (B, 8) int32
    const float* core0 = (const float*)d_in[1];  // (1, 64, 32)
    const float* mid   = (const float*)d_in[2];  // (6, 32, 64, 32)
    const float* lastc = (const float*)d_in[3];  // (32, 64, 1)
    float* out = (float*)d_out;                  // (B,)

    dim3 grid(B_TOTAL / 256), block(256);
    hipLaunchKernelGGL(tt_forward, grid, block, 0, stream, idx, core0, mid, lastc, out);
}

// Round 2
// 154.191 us; speedup vs baseline: 2.5383x; 2.5383x over previous
//
#include <hip/hip_runtime.h>

// StableTTLayer: TT forward, B=131072.
// R2: 8 lanes per sample. Lane g of a group owns v[4g..4g+3].
// - Matrix rows read as coalesced float4 per lane (group reads 128B contiguous).
// - v[r] broadcast via __shfl from owner lane (r>>2) within the 8-lane group.
// - idx loaded once, one int per lane (coalesced), redistributed via __shfl.
// Norm stabilization cancels exactly ((v/n)@M*n == v@M) -> skipped.

#define B_TOTAL 131072
#define NDIM 64
#define RANK 32
#define ROW_STRIDE (NDIM * RANK)          // 2048 floats between rows of one core
#define CORE_STRIDE (RANK * NDIM * RANK)  // 65536 floats between mid cores

__global__ __launch_bounds__(256) void tt_forward8(
    const int* __restrict__ idx,      // B x 8 (int32)
    const float* __restrict__ core0,  // 64 x 32
    const float* __restrict__ mid,    // 6 x 32 x 64 x 32
    const float* __restrict__ lastc,  // 32 x 64
    float* __restrict__ out)          // B
{
    const int tid   = blockIdx.x * 256 + threadIdx.x;   // 0 .. B*8-1
    const int b     = tid >> 3;
    const int g     = tid & 7;                          // lane within group
    const int lane  = threadIdx.x & 63;
    const int gbase = lane & ~7;                        // group's first lane in wave

    // one index per lane: tid == b*8 + g  -> fully coalesced
    int my_idx = idx[tid];
    my_idx = min(max(my_idx, 0), NDIM - 1);

    // ---- step 0: v = core0[c0], lane g takes elements 4g..4g+3
    const int c0 = __shfl(my_idx, gbase + 0);
    float4 v0 = *reinterpret_cast<const float4*>(core0 + c0 * RANK + g * 4);
    float vv[4] = {v0.x, v0.y, v0.z, v0.w};

    // ---- 6 mid matvecs
    #pragma unroll
    for (int t = 0; t < 6; ++t) {
        const int cc = __shfl(my_idx, gbase + 1 + t);
        const float* M = mid + t * CORE_STRIDE + cc * RANK + g * 4;

        float a0 = 0.f, a1 = 0.f, a2 = 0.f, a3 = 0.f;
        #pragma unroll
        for (int r = 0; r < RANK; ++r) {
            // broadcast v[r] from owner lane (r>>2), static element (r&3)
            const float vr = __shfl(vv[r & 3], gbase + (r >> 2));
            const float4 m = *reinterpret_cast<const float4*>(M + r * ROW_STRIDE);
            a0 = fmaf(vr, m.x, a0);
            a1 = fmaf(vr, m.y, a1);
            a2 = fmaf(vr, m.z, a2);
            a3 = fmaf(vr, m.w, a3);
        }
        vv[0] = a0; vv[1] = a1; vv[2] = a2; vv[3] = a3;
    }

    // ---- final: out[b] = sum_r v[r] * lastc[r][c7]
    const int c7 = __shfl(my_idx, gbase + 7);
    const float* L = lastc + c7;   // element r at L[r*64]
    float o = 0.f;
    o = fmaf(vv[0], L[(4 * g + 0) * NDIM], o);
    o = fmaf(vv[1], L[(4 * g + 1) * NDIM], o);
    o = fmaf(vv[2], L[(4 * g + 2) * NDIM], o);
    o = fmaf(vv[3], L[(4 * g + 3) * NDIM], o);
    // reduce across the 8 lanes of the group
    o += __shfl_xor(o, 1);
    o += __shfl_xor(o, 2);
    o += __shfl_xor(o, 4);
    if (g == 0) out[b] = o;
}

extern "C" void kernel_launch(void* const* d_in, const int* in_sizes, int n_in,
                              void* d_out, int out_size, void* d_ws, size_t ws_size,
                              hipStream_t stream) {
    const int*   idx   = (const int*)d_in[0];    // (B, 8) int32
    const float* core0 = (const float*)d_in[1];  // (1, 64, 32)
    const float* mid   = (const float*)d_in[2];  // (6, 32, 64, 32)
    const float* lastc = (const float*)d_in[3];  // (32, 64, 1)
    float* out = (float*)d_out;                  // (B,)

    dim3 grid((B_TOTAL * 8) / 256), block(256);
    hipLaunchKernelGGL(tt_forward8, grid, block, 0, stream, idx, core0, mid, lastc, out);
}

// Round 3
// 108.038 us; speedup vs baseline: 3.6227x; 1.4272x over previous
//
#include <hip/hip_runtime.h>
#include <hip/hip_fp16.h>

// StableTTLayer TT forward, B=131072. Round 3.
// R2 was L2-line/byte-rate bound (30 TB/s eff ~ L2 ceiling). R3 halves both:
//  - repack mid cores to fp16, layout [t][c][r2][s][pair]: per-(t,c) slice is
//    2KB contiguous; row-pairs (2r2,2r2+1) interleaved per s for v_dot2_f32_f16.
//  - v carried as packed fp16 per lane; rescaled by 16x per step (exact pow2,
//    undone at the end) to keep v in fp16 range (raw v decays to ~1e-10).
//  - core_last transposed to [c][r] for a coalesced final dot.
// Norm stabilization cancels exactly -> skipped (validated R1/R2).

#define B_TOTAL 131072
#define NDIM 64
#define RANK 32

typedef _Float16 half2_t __attribute__((ext_vector_type(2)));

#if defined(__has_builtin)
#if __has_builtin(__builtin_amdgcn_fdot2)
#define HAVE_FDOT2 1
#endif
#endif

union H2 { unsigned int u; half2_t h; __half2 hh; };

// ---- repack: mid fp32 [t][r][c][s] -> pk fp16 [t][c][r2][s][p] (p = row parity)
//      lastc fp32 [r][c] -> lastT fp32 [c][r]
__global__ __launch_bounds__(256) void tt_repack(
    const float* __restrict__ mid, const float* __restrict__ lastc,
    __half2* __restrict__ pk, float* __restrict__ lastT)
{
    const int i = blockIdx.x * 256 + threadIdx.x;   // 6*64*16*32 = 196608
    const int s  = i & 31;
    const int r2 = (i >> 5) & 15;
    const int c  = (i >> 9) & 63;
    const int t  = i >> 15;
    const float a = mid[(((t * 32 + 2 * r2 + 0) * 64) + c) * 32 + s];
    const float b = mid[(((t * 32 + 2 * r2 + 1) * 64) + c) * 32 + s];
    pk[i] = __float22half2_rn(make_float2(a, b));
    if (i < NDIM * RANK) {           // 2048: transpose lastc
        const int r = i & 31, cc = i >> 5;
        lastT[cc * RANK + r] = lastc[r * NDIM + cc];
    }
}

// ---- main: 8 lanes per sample; lane g owns s = 4g..4g+3 as 2 packed half2.
__global__ __launch_bounds__(256) void tt_forward_h(
    const int* __restrict__ idx,        // B x 8 int32
    const float* __restrict__ core0,    // 64 x 32 fp32
    const __half2* __restrict__ pk,     // [t][c][r2][s] pair-packed fp16
    const float* __restrict__ lastT,    // [c][r] fp32
    float* __restrict__ out)            // B
{
    const int tid   = blockIdx.x * 256 + threadIdx.x;
    const int b     = tid >> 3;
    const int g     = tid & 7;
    const int lane  = threadIdx.x & 63;
    const int gbase = lane & ~7;

    int my_idx = idx[tid];                       // coalesced: idx[b*8+g]
    my_idx = min(max(my_idx, 0), NDIM - 1);

    // v0 = core0[c0][4g..4g+3], packed to (v0,v1),(v2,v3)
    const int c0 = __shfl(my_idx, gbase + 0);
    const float4 f0 = *reinterpret_cast<const float4*>(core0 + c0 * RANK + 4 * g);
    H2 v01, v23;
    v01.hh = __float22half2_rn(make_float2(f0.x, f0.y));
    v23.hh = __float22half2_rn(make_float2(f0.z, f0.w));

    #pragma unroll
    for (int t = 0; t < 6; ++t) {
        const int cc = __shfl(my_idx, gbase + 1 + t);
        // slice base (in half2 units): ((t*64+c)*16 + r2)*32 + s
        const __half2* M = pk + ((t * 64 + cc) * 16) * 32 + 4 * g;

        float a0 = 0.f, a1 = 0.f, a2 = 0.f, a3 = 0.f;
        #pragma unroll
        for (int r2 = 0; r2 < 16; ++r2) {
            // broadcast packed pair (v[2r2], v[2r2+1]) from owner lane
            H2 vp;
            vp.u = __shfl((r2 & 1) ? v23.u : v01.u, gbase + (r2 >> 1));
            // group of 8 lanes reads one contiguous 128B line
            H2 m0, m1, m2, m3;
            const uint4 mraw = *reinterpret_cast<const uint4*>(M + r2 * 32);
            m0.u = mraw.x; m1.u = mraw.y; m2.u = mraw.z; m3.u = mraw.w;
#ifdef HAVE_FDOT2
            a0 = __builtin_amdgcn_fdot2(vp.h, m0.h, a0, false);
            a1 = __builtin_amdgcn_fdot2(vp.h, m1.h, a1, false);
            a2 = __builtin_amdgcn_fdot2(vp.h, m2.h, a2, false);
            a3 = __builtin_amdgcn_fdot2(vp.h, m3.h, a3, false);
#else
            const float vl = __low2float(vp.hh), vh = __high2float(vp.hh);
            a0 = fmaf(vl, __low2float(m0.hh), fmaf(vh, __high2float(m0.hh), a0));
            a1 = fmaf(vl, __low2float(m1.hh), fmaf(vh, __high2float(m1.hh), a1));
            a2 = fmaf(vl, __low2float(m2.hh), fmaf(vh, __high2float(m2.hh), a2));
            a3 = fmaf(vl, __low2float(m3.hh), fmaf(vh, __high2float(m3.hh), a3));
#endif
        }
        // rescale by 16 (exact) and repack; cumulative scale 16^6 = 2^24
        v01.hh = __float22half2_rn(make_float2(a0 * 16.f, a1 * 16.f));
        v23.hh = __float22half2_rn(make_float2(a2 * 16.f, a3 * 16.f));
    }

    // final: out[b] = 2^-24 * sum_r v[r] * lastT[c7][r]
    const int c7 = __shfl(my_idx, gbase + 7);
    const float4 L = *reinterpret_cast<const float4*>(lastT + c7 * RANK + 4 * g);
    float o = 0.f;
    o = fmaf(__low2float(v01.hh),  L.x, o);
    o = fmaf(__high2float(v01.hh), L.y, o);
    o = fmaf(__low2float(v23.hh),  L.z, o);
    o = fmaf(__high2float(v23.hh), L.w, o);
    o += __shfl_xor(o, 1);
    o += __shfl_xor(o, 2);
    o += __shfl_xor(o, 4);
    if (g == 0) out[b] = o * (1.0f / 16777216.0f);
}

extern "C" void kernel_launch(void* const* d_in, const int* in_sizes, int n_in,
                              void* d_out, int out_size, void* d_ws, size_t ws_size,
                              hipStream_t stream) {
    const int*   idx   = (const int*)d_in[0];    // (B, 8) int32
    const float* core0 = (const float*)d_in[1];  // (1, 64, 32)
    const float* mid   = (const float*)d_in[2];  // (6, 32, 64, 32)
    const float* lastc = (const float*)d_in[3];  // (32, 64, 1)
    float* out = (float*)d_out;

    // workspace: pk = 196608 half2 (786432 B), lastT = 2048 floats (8192 B)
    __half2* pk    = (__half2*)d_ws;
    float*   lastT = (float*)((char*)d_ws + 786432);

    hipLaunchKernelGGL(tt_repack, dim3(196608 / 256), dim3(256), 0, stream,
                       mid, lastc, pk, lastT);
    hipLaunchKernelGGL(tt_forward_h, dim3((B_TOTAL * 8) / 256), dim3(256), 0, stream,
                       idx, core0, pk, lastT, out);
}